// Round 6
// baseline (6061.604 us; speedup 1.0000x reference)
//
#include <hip/hip_runtime.h>
#include <hip/hip_bf16.h>
#include <math.h>

// B=2 T=1024 HID=2048 H=16 D=128 DV=128 R=4 CONV=4
// Inputs fp32. OUTPUT fp32 (reference returns float32; R2-R5 failed solely by
// writing bf16 into the fp32 d_out). Internal staging bf16; state fp32.

__device__ __forceinline__ unsigned short f2bf(float f) {
  unsigned u = __float_as_uint(f);
  unsigned r = (u + 0x7FFFu + ((u >> 16) & 1u)) >> 16;  // RNE
  return (unsigned short)r;
}
__device__ __forceinline__ float bf2f(unsigned short u) {
  return __uint_as_float(((unsigned)u) << 16);
}
__device__ __forceinline__ void store4(float* p, float4 v) { *(float4*)p = v; }
__device__ __forceinline__ void store4(unsigned short* p, float4 v) {
  *(ushort4*)p = make_ushort4(f2bf(v.x), f2bf(v.y), f2bf(v.z), f2bf(v.w));
}
__device__ __forceinline__ float sigmoidf(float x) { return 1.f / (1.f + expf(-x)); }
__device__ __forceinline__ float softplusf(float x) {
  return (x > 20.f) ? x : log1pf(expf(x));
}

// ---------------------------------------------------------------------------
// GEMM (NT): Y[m,n] = sum_k X[m,k]*W[n,k]. X:(M,K) f32, W:(N,K) f32.
// 128x128 block, 256 threads, 8x8/thread.
// ---------------------------------------------------------------------------
template <typename OutT>
__global__ __launch_bounds__(256) void gemm_nt(const float* __restrict__ X,
                                               const float* __restrict__ W,
                                               OutT* __restrict__ Y,
                                               int M, int N, int K) {
  __shared__ __attribute__((aligned(16))) float As[16][132];
  __shared__ __attribute__((aligned(16))) float Bs[16][132];
  const int tid = threadIdx.x;
  const int n0 = blockIdx.x * 128;
  const int m0 = blockIdx.y * 128;
  const int rg = tid >> 4;
  const int cg = tid & 15;

  float acc[8][8];
#pragma unroll
  for (int r = 0; r < 8; ++r)
#pragma unroll
    for (int c = 0; c < 8; ++c) acc[r][c] = 0.f;

  for (int k0 = 0; k0 < K; k0 += 16) {
    __syncthreads();
    for (int e = tid; e < 512; e += 256) {
      int m = e >> 2, kq = (e & 3) << 2;
      float4 xv = *(const float4*)(X + (size_t)(m0 + m) * K + k0 + kq);
      As[kq + 0][m] = xv.x; As[kq + 1][m] = xv.y;
      As[kq + 2][m] = xv.z; As[kq + 3][m] = xv.w;
    }
    for (int e = tid; e < 512; e += 256) {
      int n = e >> 2, kq = (e & 3) << 2;
      float4 wv = make_float4(0.f, 0.f, 0.f, 0.f);
      if (n0 + n < N) wv = *(const float4*)(W + (size_t)(n0 + n) * K + k0 + kq);
      Bs[kq + 0][n] = wv.x; Bs[kq + 1][n] = wv.y;
      Bs[kq + 2][n] = wv.z; Bs[kq + 3][n] = wv.w;
    }
    __syncthreads();
#pragma unroll
    for (int kk = 0; kk < 16; ++kk) {
      float a[8], bb[8];
      *(float4*)&a[0] = *(const float4*)&As[kk][rg * 8];
      *(float4*)&a[4] = *(const float4*)&As[kk][rg * 8 + 4];
      *(float4*)&bb[0] = *(const float4*)&Bs[kk][cg * 4];
      *(float4*)&bb[4] = *(const float4*)&Bs[kk][cg * 4 + 64];
#pragma unroll
      for (int r = 0; r < 8; ++r)
#pragma unroll
        for (int c = 0; c < 8; ++c) acc[r][c] = fmaf(a[r], bb[c], acc[r][c]);
    }
  }

#pragma unroll
  for (int r = 0; r < 8; ++r) {
    int m = m0 + rg * 8 + r;
    int n1 = n0 + cg * 4;
    int n2 = n0 + 64 + cg * 4;
    if (n1 < N)
      store4(Y + (size_t)m * N + n1,
             make_float4(acc[r][0], acc[r][1], acc[r][2], acc[r][3]));
    if (n2 < N)
      store4(Y + (size_t)m * N + n2,
             make_float4(acc[r][4], acc[r][5], acc[r][6], acc[r][7]));
  }
}

// ---------------------------------------------------------------------------
// Depthwise causal conv (K=4) + silu — scalar, 1 element/thread.
// ---------------------------------------------------------------------------
__global__ __launch_bounds__(256) void conv_silu_s(const unsigned short* __restrict__ X,
                                                   const float* __restrict__ Wc,
                                                   unsigned short* __restrict__ Y,
                                                   int C, int total) {
  int idx = blockIdx.x * 256 + threadIdx.x;
  if (idx >= total) return;
  int c = idx % C;
  int m = idx / C;
  int t = m & 1023;
  const float* w = Wc + (size_t)c * 4;
  float acc = w[3] * bf2f(X[idx]);
  if (t >= 1) acc = fmaf(w[2], bf2f(X[idx - C]), acc);
  if (t >= 2) acc = fmaf(w[1], bf2f(X[idx - 2 * C]), acc);
  if (t >= 3) acc = fmaf(w[0], bf2f(X[idx - 3 * C]), acc);
  Y[idx] = f2bf(acc * sigmoidf(acc));
}

// ---------------------------------------------------------------------------
// l2norm rows of 128 (bf16, in-place): x *= rsqrt(sum x^2 + 1e-6) * post
// ---------------------------------------------------------------------------
__global__ __launch_bounds__(256) void l2norm_bf16(unsigned short* __restrict__ X,
                                                   int rows, float post) {
  int row = blockIdx.x * 4 + (threadIdx.x >> 6);
  int lane = threadIdx.x & 63;
  if (row >= rows) return;
  unsigned short* p = X + (size_t)row * 128;
  float a = bf2f(p[lane]), b = bf2f(p[lane + 64]);
  float ss = fmaf(a, a, b * b);
#pragma unroll
  for (int m = 32; m; m >>= 1) ss += __shfl_xor(ss, m);
  float sc = rsqrtf(ss + 1e-6f) * post;
  p[lane] = f2bf(a * sc);
  p[lane + 64] = f2bf(b * sc);
}

// ---------------------------------------------------------------------------
// decay in-place: G = exp(-exp(alog[h]) * softplus(G + dtb[n])), (B*T, 2048)
// ---------------------------------------------------------------------------
__global__ __launch_bounds__(256) void decay_ip(float* __restrict__ G,
                                                const float* __restrict__ alog,
                                                const float* __restrict__ dtb,
                                                int total) {
  int idx = blockIdx.x * 256 + threadIdx.x;
  if (idx >= total) return;
  int n = idx & 2047;
  float A = expf(alog[n >> 7]);
  float x = G[idx] + dtb[n];
  G[idx] = expf(-A * softplusf(x));
}

__global__ __launch_bounds__(256) void sigmoid_ip(float* __restrict__ G, int total) {
  int idx = blockIdx.x * 256 + threadIdx.x;
  if (idx < total) G[idx] = sigmoidf(G[idx]);
}

// ---------------------------------------------------------------------------
// Recurrent scan — single-buffered. 256 blocks = (b,h,16-col slice).
// lane = g*16+s; 16 lanes share a column, each owns d in {4s..4s+3, 64+4s..+3}.
// ---------------------------------------------------------------------------
__device__ __forceinline__ float red16(float x) {
  x += __shfl_xor(x, 1);
  x += __shfl_xor(x, 2);
  x += __shfl_xor(x, 4);
  x += __shfl_xor(x, 8);
  return x;
}

__global__ __launch_bounds__(256) void scan_kernel(
    const unsigned short* __restrict__ Qn, const unsigned short* __restrict__ Kn,
    const unsigned short* __restrict__ Vb, const float* __restrict__ Dec,
    const float* __restrict__ BetaS, const float* __restrict__ ml,
    const float* __restrict__ alog, const float* __restrict__ dtb,
    float* __restrict__ O) {
  __shared__ __attribute__((aligned(16))) float s_q[128];
  __shared__ __attribute__((aligned(16))) float s_dec[128];
  __shared__ __attribute__((aligned(16))) float s_k[512];
  __shared__ __attribute__((aligned(16))) float s_v[512];
  __shared__ float s_beta[4];

  const int blk = blockIdx.x;
  const int cb = blk & 7;
  const int bh = blk >> 3;
  const int h = bh & 15;
  const int b = bh >> 4;
  const int tid = threadIdx.x;
  const int lane = tid & 63;
  const int wave = tid >> 6;
  const int s = lane & 15;
  const int cl = wave * 4 + (lane >> 4);
  const int col = cb * 16 + cl;
  const int d0 = s * 4;
  const int d1 = 64 + s * 4;

  const float A = expf(alog[h]);
  float dfill[8];
#pragma unroll
  for (int i = 0; i < 4; ++i) {
    dfill[i]     = expf(-A * softplusf(-10000.f + dtb[h * 128 + d0 + i]));
    dfill[4 + i] = expf(-A * softplusf(-10000.f + dtb[h * 128 + d1 + i]));
  }
  float wj[4];
  {
    float l0 = ml[h * 4 + 0], l1 = ml[h * 4 + 1];
    float l2 = ml[h * 4 + 2], l3 = ml[h * 4 + 3];
    float mx = fmaxf(fmaxf(l0, l1), fmaxf(l2, l3));
    float e0 = expf(l0 - mx), e1 = expf(l1 - mx);
    float e2 = expf(l2 - mx), e3 = expf(l3 - mx);
    float inv = 1.f / (e0 + e1 + e2 + e3);
    wj[0] = e0 * inv; wj[1] = e1 * inv; wj[2] = e2 * inv; wj[3] = e3 * inv;
  }

  float S[8];
#pragma unroll
  for (int i = 0; i < 8; ++i) S[i] = 0.f;

  for (int t = 0; t < 1024; ++t) {
    const size_t base = ((size_t)(b * 1024 + t) * 16 + h);
    __syncthreads();
    s_k[tid]       = bf2f(Kn[base * 512 + tid]);
    s_k[tid + 256] = bf2f(Kn[base * 512 + 256 + tid]);
    s_v[tid]       = bf2f(Vb[base * 512 + tid]);
    s_v[tid + 256] = bf2f(Vb[base * 512 + 256 + tid]);
    if (tid < 128)      s_q[tid] = bf2f(Qn[base * 128 + tid]);
    else                s_dec[tid - 128] = Dec[base * 128 + (tid - 128)];
    if (tid < 4) s_beta[tid] = BetaS[base * 4 + tid];
    __syncthreads();

    float qf[8];
#pragma unroll
    for (int i = 0; i < 4; ++i) { qf[i] = s_q[d0 + i]; qf[4 + i] = s_q[d1 + i]; }

    float o_acc = 0.f;
#pragma unroll
    for (int j = 0; j < 4; ++j) {
      float kf[8], dec[8];
#pragma unroll
      for (int i = 0; i < 4; ++i) {
        kf[i] = s_k[j * 128 + d0 + i];
        kf[4 + i] = s_k[j * 128 + d1 + i];
      }
      if (j == 0) {
#pragma unroll
        for (int i = 0; i < 4; ++i) { dec[i] = s_dec[d0 + i]; dec[4 + i] = s_dec[d1 + i]; }
      } else {
#pragma unroll
        for (int i = 0; i < 8; ++i) dec[i] = dfill[i];
      }
      float up = 0.f;
#pragma unroll
      for (int i = 0; i < 8; ++i) {
        S[i] *= dec[i];
        up = fmaf(kf[i], S[i], up);
      }
      float u = red16(up);
      float cc = s_beta[j] * (s_v[j * 128 + col] - u);
      float oj = 0.f;
#pragma unroll
      for (int i = 0; i < 8; ++i) {
        S[i] = fmaf(cc, kf[i], S[i]);
        oj = fmaf(qf[i], S[i], oj);
      }
      o_acc = fmaf(wj[j], oj, o_acc);
    }
    o_acc = red16(o_acc);
    if (s == 0) O[base * 128 + col] = o_acc;
  }
}

// ---------------------------------------------------------------------------
// RMS-norm (DV=128) * o_norm_w * sigmoid(gate_bf16 + g2_b), in-place on O(f32)
// ---------------------------------------------------------------------------
__global__ __launch_bounds__(256) void norm_gate(float* __restrict__ O,
                                                 const unsigned short* __restrict__ G,
                                                 const float* __restrict__ g2b,
                                                 const float* __restrict__ onw,
                                                 int rows) {
  int row = blockIdx.x * 4 + (threadIdx.x >> 6);
  int lane = threadIdx.x & 63;
  if (row >= rows) return;
  float* p = O + (size_t)row * 128;
  int m = row >> 4, h = row & 15;
  const unsigned short* gp = G + (size_t)m * 2048 + h * 128;
  const float* gb = g2b + h * 128;
  float a = p[lane], bv = p[lane + 64];
  float ss = fmaf(a, a, bv * bv);
#pragma unroll
  for (int k = 32; k; k >>= 1) ss += __shfl_xor(ss, k);
  float sc = rsqrtf(ss * (1.f / 128.f) + 1e-5f);
  float ga = sigmoidf(bf2f(gp[lane]) + gb[lane]);
  float gbv = sigmoidf(bf2f(gp[lane + 64]) + gb[lane + 64]);
  p[lane] = a * sc * onw[lane] * ga;
  p[lane + 64] = bv * sc * onw[lane + 64] * gbv;
}

// ---------------------------------------------------------------------------
extern "C" void kernel_launch(void* const* d_in, const int* in_sizes, int n_in,
                              void* d_out, int out_size, void* d_ws, size_t ws_size,
                              hipStream_t stream) {
  const float* x    = (const float*)d_in[0];
  const float* qw   = (const float*)d_in[1];
  const float* kw   = (const float*)d_in[2];
  const float* vw   = (const float*)d_in[3];
  const float* qcw  = (const float*)d_in[4];
  const float* kcw  = (const float*)d_in[5];
  const float* vcw  = (const float*)d_in[6];
  const float* f1w  = (const float*)d_in[7];
  const float* f2w  = (const float*)d_in[8];
  const float* bw   = (const float*)d_in[9];
  const float* ml   = (const float*)d_in[10];
  const float* alog = (const float*)d_in[11];
  const float* dtb  = (const float*)d_in[12];
  const float* g1w  = (const float*)d_in[13];
  const float* g2w  = (const float*)d_in[14];
  const float* g2b  = (const float*)d_in[15];
  const float* onw  = (const float*)d_in[16];
  const float* ow   = (const float*)d_in[17];
  float* out = (float*)d_out;  // fp32 output — the R2-R5 bug was writing bf16 here

  // workspace carve — peak 120 MiB.
  char* w8 = (char*)d_ws;
  unsigned short* P    = (unsigned short*)(w8);               // [0, 32M) staging
  float*          dec  = (float*)(w8);                        // [0, 16M)
  unsigned short* gate = (unsigned short*)(w8 + 16777216);    // 8 MB
  float*          beta = (float*)(w8 + 25165824);             // 512 KB
  float*          g1t  = (float*)(w8 + 25690112);             // 1 MB
  unsigned short* Kc   = (unsigned short*)(w8 + 33554432);    // 32 MB
  unsigned short* Vc   = (unsigned short*)(w8 + 67108864);    // 32 MB
  unsigned short* Qc   = (unsigned short*)(w8 + 100663296);   // 8 MB
  float*          o    = (float*)(w8 + 109051904);            // 16 MB (ends 120 MiB)
  (void)ws_size;

  const int M = 2048;
  dim3 blk(256);

  // ---- phase 1: projections + conv ----
  gemm_nt<unsigned short><<<dim3(64, 16), blk, 0, stream>>>(x, kw, P, M, 8192, 2048);
  conv_silu_s<<<65536, blk, 0, stream>>>(P, kcw, Kc, 8192, 16777216);
  gemm_nt<unsigned short><<<dim3(64, 16), blk, 0, stream>>>(x, vw, P, M, 8192, 2048);
  conv_silu_s<<<65536, blk, 0, stream>>>(P, vcw, Vc, 8192, 16777216);
  gemm_nt<unsigned short><<<dim3(16, 16), blk, 0, stream>>>(x, qw, P, M, 2048, 2048);
  conv_silu_s<<<16384, blk, 0, stream>>>(P, qcw, Qc, 2048, 4194304);

  // ---- phase 2: small projections (P region now dead) ----
  gemm_nt<float><<<dim3(1, 16), blk, 0, stream>>>(x, f1w, g1t, M, 128, 2048);
  gemm_nt<float><<<dim3(16, 16), blk, 0, stream>>>(g1t, f2w, dec, M, 2048, 128);
  decay_ip<<<16384, blk, 0, stream>>>(dec, alog, dtb, 4194304);

  gemm_nt<float><<<dim3(1, 16), blk, 0, stream>>>(x, bw, beta, M, 64, 2048);
  sigmoid_ip<<<512, blk, 0, stream>>>(beta, 131072);

  gemm_nt<float><<<dim3(1, 16), blk, 0, stream>>>(x, g1w, g1t, M, 128, 2048);
  gemm_nt<unsigned short><<<dim3(16, 16), blk, 0, stream>>>(g1t, g2w, gate, M, 2048, 128);

  // ---- l2 norms (in-place bf16) ----
  l2norm_bf16<<<8192, blk, 0, stream>>>(Qc, 32768, 0.08838834764831845f);
  l2norm_bf16<<<32768, blk, 0, stream>>>(Kc, 131072, 1.0f);

  // ---- recurrent scan ----
  scan_kernel<<<256, blk, 0, stream>>>(Qc, Kc, Vc, dec, beta, ml, alog, dtb, o);

  // ---- RMS-norm + gate ----
  norm_gate<<<8192, blk, 0, stream>>>(o, gate, g2b, onw, 32768);

  // ---- final projection -> FP32 out ----
  gemm_nt<float><<<dim3(16, 16), blk, 0, stream>>>(o, ow, out, M, 2048, 2048);
}

// Round 7
// 2774.308 us; speedup vs baseline: 2.1849x; 2.1849x over previous
//
#include <hip/hip_runtime.h>
#include <hip/hip_bf16.h>
#include <math.h>

// B=2 T=1024 HID=2048 H=16 D=128 DV=128 R=4 CONV=4
// Inputs fp32, output fp32 (R6-validated). Staging bf16, state fp32.
// R7: MFMA bf16 GEMMs (fp32->bf16 conversion in LDS staging) + barrier-free
// register-prefetch scan with DPP reductions. Conv/l2norm/decay/sigmoid/
// norm_gate kernels byte-identical to the R6-validated versions.

typedef unsigned short ushort_t;
typedef __attribute__((ext_vector_type(8))) short bf16x8;
typedef __attribute__((ext_vector_type(4))) float f32x4;

__device__ __forceinline__ unsigned short f2bf(float f) {
  unsigned u = __float_as_uint(f);
  unsigned r = (u + 0x7FFFu + ((u >> 16) & 1u)) >> 16;  // RNE
  return (unsigned short)r;
}
__device__ __forceinline__ float bf2f(unsigned short u) {
  return __uint_as_float(((unsigned)u) << 16);
}
__device__ __forceinline__ float sigmoidf(float x) { return 1.f / (1.f + expf(-x)); }
__device__ __forceinline__ float softplusf(float x) {
  return (x > 20.f) ? x : log1pf(expf(x));
}
__device__ __forceinline__ void store1(float* p, float v) { *p = v; }
__device__ __forceinline__ void store1(unsigned short* p, float v) { *p = f2bf(v); }

// ---------------------------------------------------------------------------
// MFMA GEMM (NT): Y[m,n] = sum_k X[m,k]*W[n,k]. X:(M,K) f32, W:(N,K) f32.
// fp32 -> bf16 conversion during LDS staging. 128x128 tile, 256 thr (4 waves,
// 2x2 wave grid, 4x4 16x16 frags/wave), BK=32. LDS rows padded to 40 bf16.
// M, K multiples of 128/32; N arbitrary (guarded).
// ---------------------------------------------------------------------------
template <typename OutT>
__global__ __launch_bounds__(256) void gemm_mfma(const float* __restrict__ A,
                                                 const float* __restrict__ B,
                                                 OutT* __restrict__ Y,
                                                 int M, int N, int K) {
  __shared__ __attribute__((aligned(16))) unsigned short As[128 * 40];
  __shared__ __attribute__((aligned(16))) unsigned short Bs[128 * 40];
  const int tid = threadIdx.x;
  const int lane = tid & 63;
  const int wave = tid >> 6;
  const int quad = lane >> 4;
  const int l16 = lane & 15;
  const int wm = wave >> 1;   // 0..1
  const int wn = wave & 1;    // 0..1
  const int n0 = blockIdx.x * 128;
  const int m0 = blockIdx.y * 128;

  f32x4 acc[4][4];
#pragma unroll
  for (int i = 0; i < 4; ++i)
#pragma unroll
    for (int j = 0; j < 4; ++j) acc[i][j] = (f32x4){0.f, 0.f, 0.f, 0.f};

  for (int k0 = 0; k0 < K; k0 += 32) {
    __syncthreads();
    // stage A tile (128 x 32): 512 8-element units, 2 per thread
#pragma unroll
    for (int u = tid; u < 512; u += 256) {
      int m = u >> 2, c = u & 3;
      const float* src = A + (size_t)(m0 + m) * K + k0 + c * 8;
      float4 a0 = *(const float4*)(src);
      float4 a1 = *(const float4*)(src + 4);
      *(ushort4*)&As[m * 40 + c * 8] =
          make_ushort4(f2bf(a0.x), f2bf(a0.y), f2bf(a0.z), f2bf(a0.w));
      *(ushort4*)&As[m * 40 + c * 8 + 4] =
          make_ushort4(f2bf(a1.x), f2bf(a1.y), f2bf(a1.z), f2bf(a1.w));
    }
    // stage B tile (128 x 32), rows >= N zero-filled
#pragma unroll
    for (int u = tid; u < 512; u += 256) {
      int n = u >> 2, c = u & 3;
      float4 b0 = make_float4(0.f, 0.f, 0.f, 0.f);
      float4 b1 = b0;
      if (n0 + n < N) {
        const float* src = B + (size_t)(n0 + n) * K + k0 + c * 8;
        b0 = *(const float4*)(src);
        b1 = *(const float4*)(src + 4);
      }
      *(ushort4*)&Bs[n * 40 + c * 8] =
          make_ushort4(f2bf(b0.x), f2bf(b0.y), f2bf(b0.z), f2bf(b0.w));
      *(ushort4*)&Bs[n * 40 + c * 8 + 4] =
          make_ushort4(f2bf(b1.x), f2bf(b1.y), f2bf(b1.z), f2bf(b1.w));
    }
    __syncthreads();

    bf16x8 av[4], bv[4];
#pragma unroll
    for (int i = 0; i < 4; ++i)
      av[i] = *(const bf16x8*)&As[(wm * 64 + i * 16 + l16) * 40 + quad * 8];
#pragma unroll
    for (int j = 0; j < 4; ++j)
      bv[j] = *(const bf16x8*)&Bs[(wn * 64 + j * 16 + l16) * 40 + quad * 8];
#pragma unroll
    for (int i = 0; i < 4; ++i)
#pragma unroll
      for (int j = 0; j < 4; ++j)
        acc[i][j] = __builtin_amdgcn_mfma_f32_16x16x32_bf16(av[i], bv[j], acc[i][j], 0, 0, 0);
  }

  // epilogue: D[row=quad*4+reg][col=l16] per 16x16 tile
#pragma unroll
  for (int i = 0; i < 4; ++i)
#pragma unroll
    for (int j = 0; j < 4; ++j) {
      int rr = m0 + wm * 64 + i * 16 + quad * 4;
      int cc = n0 + wn * 64 + j * 16 + l16;
      if (cc < N) {
#pragma unroll
        for (int r = 0; r < 4; ++r)
          store1(Y + (size_t)(rr + r) * N + cc, acc[i][j][r]);
      }
    }
}

// ---------------------------------------------------------------------------
// Depthwise causal conv (K=4) + silu — scalar (R6-validated).
// ---------------------------------------------------------------------------
__global__ __launch_bounds__(256) void conv_silu_s(const unsigned short* __restrict__ X,
                                                   const float* __restrict__ Wc,
                                                   unsigned short* __restrict__ Y,
                                                   int C, int total) {
  int idx = blockIdx.x * 256 + threadIdx.x;
  if (idx >= total) return;
  int c = idx % C;
  int m = idx / C;
  int t = m & 1023;
  const float* w = Wc + (size_t)c * 4;
  float acc = w[3] * bf2f(X[idx]);
  if (t >= 1) acc = fmaf(w[2], bf2f(X[idx - C]), acc);
  if (t >= 2) acc = fmaf(w[1], bf2f(X[idx - 2 * C]), acc);
  if (t >= 3) acc = fmaf(w[0], bf2f(X[idx - 3 * C]), acc);
  Y[idx] = f2bf(acc * sigmoidf(acc));
}

// ---------------------------------------------------------------------------
// l2norm rows of 128 (bf16, in-place) — R6-validated.
// ---------------------------------------------------------------------------
__global__ __launch_bounds__(256) void l2norm_bf16(unsigned short* __restrict__ X,
                                                   int rows, float post) {
  int row = blockIdx.x * 4 + (threadIdx.x >> 6);
  int lane = threadIdx.x & 63;
  if (row >= rows) return;
  unsigned short* p = X + (size_t)row * 128;
  float a = bf2f(p[lane]), b = bf2f(p[lane + 64]);
  float ss = fmaf(a, a, b * b);
#pragma unroll
  for (int m = 32; m; m >>= 1) ss += __shfl_xor(ss, m);
  float sc = rsqrtf(ss + 1e-6f) * post;
  p[lane] = f2bf(a * sc);
  p[lane + 64] = f2bf(b * sc);
}

// ---------------------------------------------------------------------------
// decay in-place (R6-validated).
// ---------------------------------------------------------------------------
__global__ __launch_bounds__(256) void decay_ip(float* __restrict__ G,
                                                const float* __restrict__ alog,
                                                const float* __restrict__ dtb,
                                                int total) {
  int idx = blockIdx.x * 256 + threadIdx.x;
  if (idx >= total) return;
  int n = idx & 2047;
  float A = expf(alog[n >> 7]);
  float x = G[idx] + dtb[n];
  G[idx] = expf(-A * softplusf(x));
}

__global__ __launch_bounds__(256) void sigmoid_ip(float* __restrict__ G, int total) {
  int idx = blockIdx.x * 256 + threadIdx.x;
  if (idx < total) G[idx] = sigmoidf(G[idx]);
}

// ---------------------------------------------------------------------------
// Recurrent scan v2 — barrier-free, LDS-free, register double-buffered.
// 1024 blocks x 64 threads. block -> (b,h, 4-col group); lane = g*16+s.
// 16-lane group shares column col, lane owns d in {4s..4s+3, 64+4s..64+4s+3}.
// Reductions over the 16-lane group via DPP adds:
//   xor1 = quad_perm[1,0,3,2] (0xB1), xor2 = quad_perm[2,3,0,1] (0x4E),
//   stage3 = row_half_mirror (0x141; valid after quad is summed),
//   stage4 = row_mirror (0x140; valid after 8-group is summed).
// ---------------------------------------------------------------------------
template <int CTRL>
__device__ __forceinline__ float dppadd(float x) {
  int y = __builtin_amdgcn_update_dpp(0, __float_as_int(x), CTRL, 0xF, 0xF, true);
  return x + __int_as_float(y);
}
__device__ __forceinline__ float red16(float x) {
  x = dppadd<0xB1>(x);
  x = dppadd<0x4E>(x);
  x = dppadd<0x141>(x);
  x = dppadd<0x140>(x);
  return x;
}

struct Pref {
  ushort4 k[8];   // k[j] segments d0/d1
  ushort4 q[2];
  float4 d[2];
  float4 beta;
  unsigned short v[4];
};

__global__ __launch_bounds__(64) void scan_kernel2(
    const unsigned short* __restrict__ Qn, const unsigned short* __restrict__ Kn,
    const unsigned short* __restrict__ Vb, const float* __restrict__ Dec,
    const float* __restrict__ BetaS, const float* __restrict__ ml,
    const float* __restrict__ alog, const float* __restrict__ dtb,
    float* __restrict__ O) {
  const int blk = blockIdx.x;
  const int cq = blk & 31;   // 32 groups of 4 columns
  const int bh = blk >> 5;   // 0..31
  const int h = bh & 15;
  const int b = bh >> 4;
  const int lane = threadIdx.x;
  const int s = lane & 15;
  const int g = lane >> 4;
  const int col = cq * 4 + g;
  const int d0 = s * 4;
  const int d1 = 64 + s * 4;

  const float A = expf(alog[h]);
  float dfill[8];
#pragma unroll
  for (int i = 0; i < 4; ++i) {
    dfill[i]     = expf(-A * softplusf(-10000.f + dtb[h * 128 + d0 + i]));
    dfill[4 + i] = expf(-A * softplusf(-10000.f + dtb[h * 128 + d1 + i]));
  }
  float wj[4];
  {
    float l0 = ml[h * 4 + 0], l1 = ml[h * 4 + 1];
    float l2 = ml[h * 4 + 2], l3 = ml[h * 4 + 3];
    float mx = fmaxf(fmaxf(l0, l1), fmaxf(l2, l3));
    float e0 = expf(l0 - mx), e1 = expf(l1 - mx);
    float e2 = expf(l2 - mx), e3 = expf(l3 - mx);
    float inv = 1.f / (e0 + e1 + e2 + e3);
    wj[0] = e0 * inv; wj[1] = e1 * inv; wj[2] = e2 * inv; wj[3] = e3 * inv;
  }

  float S[8];
#pragma unroll
  for (int i = 0; i < 8; ++i) S[i] = 0.f;

  auto LD = [&](int t, Pref& P) {
    const size_t base = ((size_t)(b * 1024 + t) * 16 + h);
    const unsigned short* kp = Kn + base * 512;
    const unsigned short* vp = Vb + base * 512;
#pragma unroll
    for (int j = 0; j < 4; ++j) {
      P.k[2 * j]     = *(const ushort4*)(kp + j * 128 + d0);
      P.k[2 * j + 1] = *(const ushort4*)(kp + j * 128 + d1);
      P.v[j] = vp[j * 128 + col];
    }
    P.q[0] = *(const ushort4*)(Qn + base * 128 + d0);
    P.q[1] = *(const ushort4*)(Qn + base * 128 + d1);
    P.d[0] = *(const float4*)(Dec + base * 128 + d0);
    P.d[1] = *(const float4*)(Dec + base * 128 + d1);
    P.beta = *(const float4*)(BetaS + base * 4);
  };

  auto STEP = [&](const Pref& P, int t) {
    float qf[8], kf[8], dec[8];
    qf[0] = bf2f(P.q[0].x); qf[1] = bf2f(P.q[0].y);
    qf[2] = bf2f(P.q[0].z); qf[3] = bf2f(P.q[0].w);
    qf[4] = bf2f(P.q[1].x); qf[5] = bf2f(P.q[1].y);
    qf[6] = bf2f(P.q[1].z); qf[7] = bf2f(P.q[1].w);
    float o_acc = 0.f;
    const float bcoef[4] = {P.beta.x, P.beta.y, P.beta.z, P.beta.w};
#pragma unroll
    for (int j = 0; j < 4; ++j) {
      kf[0] = bf2f(P.k[2 * j].x); kf[1] = bf2f(P.k[2 * j].y);
      kf[2] = bf2f(P.k[2 * j].z); kf[3] = bf2f(P.k[2 * j].w);
      kf[4] = bf2f(P.k[2 * j + 1].x); kf[5] = bf2f(P.k[2 * j + 1].y);
      kf[6] = bf2f(P.k[2 * j + 1].z); kf[7] = bf2f(P.k[2 * j + 1].w);
      if (j == 0) {
        dec[0] = P.d[0].x; dec[1] = P.d[0].y; dec[2] = P.d[0].z; dec[3] = P.d[0].w;
        dec[4] = P.d[1].x; dec[5] = P.d[1].y; dec[6] = P.d[1].z; dec[7] = P.d[1].w;
      } else {
#pragma unroll
        for (int i = 0; i < 8; ++i) dec[i] = dfill[i];
      }
      float upA = 0.f, upB = 0.f;
#pragma unroll
      for (int i = 0; i < 4; ++i) {
        S[i] *= dec[i];
        upA = fmaf(kf[i], S[i], upA);
        S[4 + i] *= dec[4 + i];
        upB = fmaf(kf[4 + i], S[4 + i], upB);
      }
      float u = red16(upA + upB);
      float cc = bcoef[j] * (bf2f(P.v[j]) - u);
      float ojA = 0.f, ojB = 0.f;
#pragma unroll
      for (int i = 0; i < 4; ++i) {
        S[i] = fmaf(cc, kf[i], S[i]);
        ojA = fmaf(qf[i], S[i], ojA);
        S[4 + i] = fmaf(cc, kf[4 + i], S[4 + i]);
        ojB = fmaf(qf[4 + i], S[4 + i], ojB);
      }
      o_acc = fmaf(wj[j], ojA + ojB, o_acc);
    }
    o_acc = red16(o_acc);
    if (s == 0) {
      const size_t base = ((size_t)(b * 1024 + t) * 16 + h);
      O[base * 128 + col] = o_acc;
    }
  };

  Pref P0, P1;
  LD(0, P0);
  for (int t = 0; t < 1024; t += 2) {
    LD(t + 1, P1);
    STEP(P0, t);
    if (t + 2 < 1024) LD(t + 2, P0);
    STEP(P1, t + 1);
  }
}

// ---------------------------------------------------------------------------
// RMS-norm * o_norm_w * sigmoid(gate + g2_b), in-place on O(f32) — R6-validated.
// ---------------------------------------------------------------------------
__global__ __launch_bounds__(256) void norm_gate(float* __restrict__ O,
                                                 const unsigned short* __restrict__ G,
                                                 const float* __restrict__ g2b,
                                                 const float* __restrict__ onw,
                                                 int rows) {
  int row = blockIdx.x * 4 + (threadIdx.x >> 6);
  int lane = threadIdx.x & 63;
  if (row >= rows) return;
  float* p = O + (size_t)row * 128;
  int m = row >> 4, h = row & 15;
  const unsigned short* gp = G + (size_t)m * 2048 + h * 128;
  const float* gb = g2b + h * 128;
  float a = p[lane], bv = p[lane + 64];
  float ss = fmaf(a, a, bv * bv);
#pragma unroll
  for (int k = 32; k; k >>= 1) ss += __shfl_xor(ss, k);
  float sc = rsqrtf(ss * (1.f / 128.f) + 1e-5f);
  float ga = sigmoidf(bf2f(gp[lane]) + gb[lane]);
  float gbv = sigmoidf(bf2f(gp[lane + 64]) + gb[lane + 64]);
  p[lane] = a * sc * onw[lane] * ga;
  p[lane + 64] = bv * sc * onw[lane + 64] * gbv;
}

// ---------------------------------------------------------------------------
extern "C" void kernel_launch(void* const* d_in, const int* in_sizes, int n_in,
                              void* d_out, int out_size, void* d_ws, size_t ws_size,
                              hipStream_t stream) {
  const float* x    = (const float*)d_in[0];
  const float* qw   = (const float*)d_in[1];
  const float* kw   = (const float*)d_in[2];
  const float* vw   = (const float*)d_in[3];
  const float* qcw  = (const float*)d_in[4];
  const float* kcw  = (const float*)d_in[5];
  const float* vcw  = (const float*)d_in[6];
  const float* f1w  = (const float*)d_in[7];
  const float* f2w  = (const float*)d_in[8];
  const float* bw   = (const float*)d_in[9];
  const float* ml   = (const float*)d_in[10];
  const float* alog = (const float*)d_in[11];
  const float* dtb  = (const float*)d_in[12];
  const float* g1w  = (const float*)d_in[13];
  const float* g2w  = (const float*)d_in[14];
  const float* g2b  = (const float*)d_in[15];
  const float* onw  = (const float*)d_in[16];
  const float* ow   = (const float*)d_in[17];
  float* out = (float*)d_out;  // fp32 output

  // workspace carve — peak 120 MiB (R6-validated layout).
  char* w8 = (char*)d_ws;
  unsigned short* P    = (unsigned short*)(w8);               // [0, 32M) staging
  float*          dec  = (float*)(w8);                        // [0, 16M)
  unsigned short* gate = (unsigned short*)(w8 + 16777216);    // 8 MB
  float*          beta = (float*)(w8 + 25165824);             // 512 KB
  float*          g1t  = (float*)(w8 + 25690112);             // 1 MB
  unsigned short* Kc   = (unsigned short*)(w8 + 33554432);    // 32 MB
  unsigned short* Vc   = (unsigned short*)(w8 + 67108864);    // 32 MB
  unsigned short* Qc   = (unsigned short*)(w8 + 100663296);   // 8 MB
  float*          o    = (float*)(w8 + 109051904);            // 16 MB (ends 120 MiB)
  (void)ws_size;

  const int M = 2048;
  dim3 blk(256);

  // ---- phase 1: projections (MFMA) + conv ----
  gemm_mfma<unsigned short><<<dim3(64, 16), blk, 0, stream>>>(x, kw, P, M, 8192, 2048);
  conv_silu_s<<<65536, blk, 0, stream>>>(P, kcw, Kc, 8192, 16777216);
  gemm_mfma<unsigned short><<<dim3(64, 16), blk, 0, stream>>>(x, vw, P, M, 8192, 2048);
  conv_silu_s<<<65536, blk, 0, stream>>>(P, vcw, Vc, 8192, 16777216);
  gemm_mfma<unsigned short><<<dim3(16, 16), blk, 0, stream>>>(x, qw, P, M, 2048, 2048);
  conv_silu_s<<<16384, blk, 0, stream>>>(P, qcw, Qc, 2048, 4194304);

  // ---- phase 2: small projections (P region now dead) ----
  gemm_mfma<float><<<dim3(1, 16), blk, 0, stream>>>(x, f1w, g1t, M, 128, 2048);
  gemm_mfma<float><<<dim3(16, 16), blk, 0, stream>>>(g1t, f2w, dec, M, 2048, 128);
  decay_ip<<<16384, blk, 0, stream>>>(dec, alog, dtb, 4194304);

  gemm_mfma<float><<<dim3(1, 16), blk, 0, stream>>>(x, bw, beta, M, 64, 2048);
  sigmoid_ip<<<512, blk, 0, stream>>>(beta, 131072);

  gemm_mfma<float><<<dim3(1, 16), blk, 0, stream>>>(x, g1w, g1t, M, 128, 2048);
  gemm_mfma<unsigned short><<<dim3(16, 16), blk, 0, stream>>>(g1t, g2w, gate, M, 2048, 128);

  // ---- l2 norms (in-place bf16) ----
  l2norm_bf16<<<8192, blk, 0, stream>>>(Qc, 32768, 0.08838834764831845f);
  l2norm_bf16<<<32768, blk, 0, stream>>>(Kc, 131072, 1.0f);

  // ---- recurrent scan (barrier-free, register-prefetched) ----
  scan_kernel2<<<1024, dim3(64), 0, stream>>>(Qc, Kc, Vc, dec, beta, ml, alog, dtb, o);

  // ---- RMS-norm + gate ----
  norm_gate<<<8192, blk, 0, stream>>>(o, gate, g2b, onw, 32768);

  // ---- final projection -> fp32 out ----
  gemm_mfma<float><<<dim3(16, 16), blk, 0, stream>>>(o, ow, out, M, 2048, 2048);
}